// Round 1
// baseline (1781.490 us; speedup 1.0000x reference)
//
#include <hip/hip_runtime.h>

// MyRNNCell via MFMA f16 on gfx950 — v2: latency-trimmed serial loop.
//
//   Wh = W[0:256], Wx = W[256:384];  h_{t+1} = tanh([h_t | x_t] @ W + bias)
//
// 16 workgroups x 16 batches (MFMA M=16 is the batch-parallel quantum).
// 256 threads = 4 waves; wave w owns units [64w, 64w+64) = 4 N-tiles of 16.
// K = 384 = 12 slices of 32:  k 0..255 = h,  k 256..383 = x_t.
//
// v2 changes vs the 1449us baseline (which measured 27% MfmaUtil / 36%
// VALUBusy / ~64% stall on the 16 active CUs):
//  1. LDS-only barrier (s_waitcnt lgkmcnt(0); s_barrier) instead of
//     __syncthreads(): hipcc's __syncthreads drains vmcnt(0), i.e. waits
//     for the 16 scattered fp32 out-stores to ack every step. Nothing
//     in-kernel reads them -> fire-and-forget.
//  2. x-projection pipelined one step ahead (3 LDS buffers): the 4
//     x-K-slices don't depend on h_t, so step t computes step t+1's
//     x-partial (16 independent MFMAs, interleaved into the h-chain's
//     latency gaps). Critical chain per step: 8 ds_reads + 8-deep MFMA
//     chain (was 12 + 12-deep).
//  3. t-loop unrolled by 3 so LDS buffer bases are compile-time offsets.
//
// Buffer schedule (buf i = t%3): buf holds {h_t in slices 0..7, x_t in
// slices 8..11}. At step t: read h_t from cur, read x_{t+1} frags from
// nxt (published at t-1), publish h_{t+1} -> nxt slices 0..7, publish
// x_{t+2} (regs, loaded at t-1) -> nx2 slices 8..11. All writes target
// slots whose last readers finished before the previous barrier.
//
// fp16 (not bf16): 2^-11 quantization keeps recurrent error ~1e-3 << 2e-2.
// W fragments (B operand) live in registers: 4 tiles x 12 slices x 4 VGPR.

typedef _Float16 half8 __attribute__((ext_vector_type(8)));
typedef float floatx4 __attribute__((ext_vector_type(4)));

constexpr int B = 256, T = 1024, D = 128, U = 256;
constexpr int NSL = (U + D) / 32;      // 12 K-slices
constexpr int QS  = 16 * 16 + 16;      // 272 B quad stride (+16 pad: bank spread)
constexpr int SS  = 4 * QS;            // 1088 B slice stride
constexpr int BUF = NSL * SS;          // 13056 B per A-buffer

__device__ __forceinline__ float fexp2(float v) {
#if __has_builtin(__builtin_amdgcn_exp2f)
    return __builtin_amdgcn_exp2f(v);
#else
    return exp2f(v);
#endif
}
__device__ __forceinline__ float frcp(float v) {
#if __has_builtin(__builtin_amdgcn_rcpf)
    return __builtin_amdgcn_rcpf(v);
#else
    return 1.0f / v;
#endif
}
// tanh(v) = 1 - 2/(e^{2v}+1).  exp2->inf and rcp(inf)=0 make saturation
// exact at both ends without clamping.
__device__ __forceinline__ float fast_tanh(float v) {
    float e = fexp2(2.8853900817779268f * v);   // e^{2v} = 2^{2v*log2(e)}
    return 1.0f - 2.0f * frcp(e + 1.0f);
}

__device__ __forceinline__ void cvt_write8(void* dst, float4 lo, float4 hi) {
    half8 h;
    h[0] = (_Float16)lo.x; h[1] = (_Float16)lo.y;
    h[2] = (_Float16)lo.z; h[3] = (_Float16)lo.w;
    h[4] = (_Float16)hi.x; h[5] = (_Float16)hi.y;
    h[6] = (_Float16)hi.z; h[7] = (_Float16)hi.w;
    *reinterpret_cast<half8*>(dst) = h;
}

// Barrier that only drains LDS ops. __syncthreads() would emit
// s_waitcnt vmcnt(0) expcnt(0) lgkmcnt(0) and stall on the out-stores.
__device__ __forceinline__ void lds_barrier() {
    asm volatile("s_waitcnt lgkmcnt(0)\n\ts_barrier" ::: "memory");
}

__global__ __launch_bounds__(256, 1)
void rnn_mfma_kernel(const float* __restrict__ x, const float* __restrict__ h0,
                     const float* __restrict__ W, const float* __restrict__ bias,
                     float* __restrict__ out)
{
    __shared__ __align__(16) unsigned char lds[3 * BUF];

    const int tid  = threadIdx.x;
    const int lane = tid & 63;
    const int wv   = tid >> 6;     // wave 0..3, owns units [64wv, 64wv+64)
    const int l15  = lane & 15;
    const int quad = lane >> 4;
    const int b0   = blockIdx.x * 16;

    // ---- W fragments (B operand) + bias, one-time ----
    half8 wf[4][NSL];
    float bv[4];
#pragma unroll
    for (int nt = 0; nt < 4; ++nt) {
        const int n = 64 * wv + 16 * nt + l15;
        bv[nt] = bias[n];
#pragma unroll
        for (int s = 0; s < NSL; ++s) {
            half8 f;
#pragma unroll
            for (int j = 0; j < 8; ++j) {
                const int k = 32 * s + 8 * quad + j;
                f[j] = (_Float16)W[(size_t)k * U + n];
            }
            wf[nt][s] = f;
        }
    }

    // ---- stage h0+x_0 -> buf0, x_1 -> buf1; prefetch x_2 into regs ----
    const int sm = tid >> 4;   // staging batch row 0..15
    const int sc = tid & 15;   // staging chunk
#pragma unroll
    for (int cc = sc; cc < 32; cc += 16) {           // h0: 32 chunks of 8 units
        const float* hp = h0 + (size_t)(b0 + sm) * U + 8 * cc;
        cvt_write8(lds + (cc >> 2) * SS + (cc & 3) * QS + sm * 16,
                   *reinterpret_cast<const float4*>(hp),
                   *reinterpret_cast<const float4*>(hp + 4));
    }
    const float* xbase = x + (size_t)(b0 + sm) * T * D + 8 * sc;
    const int xslot = (8 + (sc >> 2)) * SS + (sc & 3) * QS + sm * 16;
    cvt_write8(lds + xslot,
               *reinterpret_cast<const float4*>(xbase),
               *reinterpret_cast<const float4*>(xbase + 4));
    cvt_write8(lds + BUF + xslot,
               *reinterpret_cast<const float4*>(xbase + D),
               *reinterpret_cast<const float4*>(xbase + D + 4));

    float4 p0 = *reinterpret_cast<const float4*>(xbase + 2 * D);
    float4 p1 = *reinterpret_cast<const float4*>(xbase + 2 * D + 4);

    __syncthreads();

    const int aoff = quad * QS + l15 * 16;

    // ---- precompute x-partial for step 0 (buf0 slices 8..11) ----
    floatx4 accx[4];
    {
        half8 ax[4];
#pragma unroll
        for (int s = 0; s < 4; ++s)
            ax[s] = *reinterpret_cast<const half8*>(lds + aoff + (8 + s) * SS);
#pragma unroll
        for (int nt = 0; nt < 4; ++nt)
            accx[nt] = (floatx4){bv[nt], bv[nt], bv[nt], bv[nt]};
#pragma unroll
        for (int s = 0; s < 4; ++s)
#pragma unroll
            for (int nt = 0; nt < 4; ++nt)
                accx[nt] = __builtin_amdgcn_mfma_f32_16x16x32_f16(
                               ax[s], wf[nt][8 + s], accx[nt], 0, 0, 0);
    }

    // One step. co/no/n2o are the byte offsets of buffers t%3, (t+1)%3,
    // (t+2)%3 — passed as literals so ds ops get immediate offsets.
#define STEP(tt, co, no, n2o)                                                  \
    do {                                                                       \
        const int t_ = (tt);                                                   \
        const int tp_ = (t_ + 3 < T) ? (t_ + 3) : (T - 1);                     \
        float4 q0 = *reinterpret_cast<const float4*>(xbase + (size_t)D * tp_); \
        float4 q1 = *reinterpret_cast<const float4*>(xbase + (size_t)D * tp_ + 4);\
        half8 ah[8];                                                           \
        _Pragma("unroll")                                                      \
        for (int s = 0; s < 8; ++s)                                            \
            ah[s] = *reinterpret_cast<const half8*>(lds + (co) + aoff + s * SS);\
        half8 ax[4];                                                           \
        _Pragma("unroll")                                                      \
        for (int s = 0; s < 4; ++s)                                            \
            ax[s] = *reinterpret_cast<const half8*>(lds + (no) + aoff + (8 + s) * SS);\
        floatx4 acc[4], accn[4];                                               \
        _Pragma("unroll")                                                      \
        for (int nt = 0; nt < 4; ++nt) {                                       \
            acc[nt]  = accx[nt];                                               \
            accn[nt] = (floatx4){bv[nt], bv[nt], bv[nt], bv[nt]};              \
        }                                                                      \
        _Pragma("unroll")                                                      \
        for (int s = 0; s < 8; ++s) {                                          \
            _Pragma("unroll")                                                  \
            for (int nt = 0; nt < 4; ++nt)                                     \
                acc[nt] = __builtin_amdgcn_mfma_f32_16x16x32_f16(              \
                              ah[s], wf[nt][s], acc[nt], 0, 0, 0);             \
            if (s < 4) {                                                       \
                _Pragma("unroll")                                              \
                for (int nt = 0; nt < 4; ++nt)                                 \
                    accn[nt] = __builtin_amdgcn_mfma_f32_16x16x32_f16(         \
                                   ax[s], wf[nt][8 + s], accn[nt], 0, 0, 0);   \
            }                                                                  \
        }                                                                      \
        _Pragma("unroll")                                                      \
        for (int nt = 0; nt < 4; ++nt) accx[nt] = accn[nt];                    \
        float* orow = out + (size_t)t_ * U;                                    \
        _Pragma("unroll")                                                      \
        for (int nt = 0; nt < 4; ++nt) {                                       \
            const int n = 64 * wv + 16 * nt + l15;                             \
            _Pragma("unroll")                                                  \
            for (int r = 0; r < 4; ++r) {                                      \
                const int m = 4 * quad + r;                                    \
                const float h = fast_tanh(acc[nt][r]);                         \
                *reinterpret_cast<_Float16*>(                                  \
                    lds + (no) + (n >> 5) * SS + ((n >> 3) & 3) * QS           \
                        + m * 16 + (n & 7) * 2) = (_Float16)h;                 \
                orow[(size_t)(b0 + m) * T * U + n] = h;                        \
            }                                                                  \
        }                                                                      \
        cvt_write8(lds + (n2o) + xslot, p0, p1);                               \
        p0 = q0; p1 = q1;                                                      \
        lds_barrier();                                                         \
    } while (0)

    // T-1 = 1023 = 3*341 steps in the rotated loop, then one tail step.
    for (int tb = 0; tb < T - 1; tb += 3) {
        STEP(tb,     0,       BUF,     2 * BUF);
        STEP(tb + 1, BUF,     2 * BUF, 0);
        STEP(tb + 2, 2 * BUF, 0,       BUF);
    }
    STEP(T - 1, 0, BUF, 2 * BUF);
#undef STEP
}

extern "C" void kernel_launch(void* const* d_in, const int* in_sizes, int n_in,
                              void* d_out, int out_size, void* d_ws, size_t ws_size,
                              hipStream_t stream) {
    const float* x    = (const float*)d_in[0];
    const float* h0   = (const float*)d_in[1];
    const float* W    = (const float*)d_in[2];
    const float* bias = (const float*)d_in[3];
    float* out = (float*)d_out;

    hipLaunchKernelGGL(rnn_mfma_kernel, dim3(B / 16), dim3(256), 0, stream,
                       x, h0, W, bias, out);
}

// Round 2
// 1264.326 us; speedup vs baseline: 1.4090x; 1.4090x over previous
//
#include <hip/hip_runtime.h>

// MyRNNCell via MFMA f16 on gfx950 — v3: round-0 structure + 2 waves/SIMD.
//
//   Wh = W[0:256], Wx = W[256:384];  h_{t+1} = tanh([h_t | x_t] @ W + bias)
//
// 16 workgroups x 16 batches (MFMA M=16 is the batch-parallel quantum).
// v3: 512 threads = 8 waves (2 waves/SIMD); wave w owns units [32w, 32w+32)
// = 2 N-tiles of 16.  Total per-CU work unchanged (192 MFMA/step); the
// second wave per SIMD hides the serial non-MFMA phases (tanh epilogue,
// scattered ds_write_b16 h-publish, store drain, ds_read latency) under
// the other wave's MFMAs.  Round-0 measured 1 wave/SIMD: MfmaUtil 27%,
// VALUBusy 36%, ~64% stall on active CUs -> TLP is the lever.
//
// v2 post-mortem (1522us, REGRESSED vs 1197us): 3-buffer x-pipelining +
// lgkmcnt-only barrier + unroll-by-3 added ~350us of stall with identical
// MFMA work (likely vmem back-pressure relocated to top-of-step loads +
// tripled body).  Fully reverted; this kernel is round-0 except the wave
// split.
//
// K = 384 = 12 slices of 32:  k 0..255 = h,  k 256..383 = x_t.
// Per step: 12 A-frags from LDS (A[m=lane&15][k=(lane>>4)*8+j], m120-
// verified layout), 24 mfma_f32_16x16x32_f16/wave accumulating from
// C=bias, tanh epilogue (C-layout: n=lane&15, m=(lane>>4)*4+reg, m89-
// verified), fp32 store, publish h_new as f16 into the A-buffer for t+1.
// x_{t+1} staged into A slots 256..383; double-buffered; ONE barrier/step.
// x prefetched 2 steps ahead (issue at t, LDS-publish at t+1).
//
// fp16 (not bf16): 2^-11 quantization keeps recurrent error ~1e-3 << 2e-2.
// W fragments (B operand, B[k][n]: n=lane&15, k=(lane>>4)*8+j) live in
// registers: 2 tiles x 12 slices x 4 VGPR = 96 VGPRs; fits 2 waves/SIMD.

typedef _Float16 half8 __attribute__((ext_vector_type(8)));
typedef _Float16 half4v __attribute__((ext_vector_type(4)));
typedef float floatx4 __attribute__((ext_vector_type(4)));

constexpr int B = 256, T = 1024, D = 128, U = 256;
constexpr int NSL = (U + D) / 32;      // 12 K-slices
constexpr int QS  = 16 * 16 + 16;      // 272 B quad stride (+16 pad: bank spread)
constexpr int SS  = 4 * QS;            // 1088 B slice stride
constexpr int BUF = NSL * SS;          // 13056 B per A-buffer

__device__ __forceinline__ float fexp2(float v) {
#if __has_builtin(__builtin_amdgcn_exp2f)
    return __builtin_amdgcn_exp2f(v);
#else
    return exp2f(v);
#endif
}
__device__ __forceinline__ float frcp(float v) {
#if __has_builtin(__builtin_amdgcn_rcpf)
    return __builtin_amdgcn_rcpf(v);
#else
    return 1.0f / v;
#endif
}
// tanh(v) = 1 - 2/(e^{2v}+1).  exp2->inf and rcp(inf)=0 make saturation
// exact at both ends without clamping.
__device__ __forceinline__ float fast_tanh(float v) {
    float e = fexp2(2.8853900817779268f * v);   // e^{2v} = 2^{2v*log2(e)}
    return 1.0f - 2.0f * frcp(e + 1.0f);
}

__device__ __forceinline__ void cvt_write8(void* dst, float4 lo, float4 hi) {
    half8 h;
    h[0] = (_Float16)lo.x; h[1] = (_Float16)lo.y;
    h[2] = (_Float16)lo.z; h[3] = (_Float16)lo.w;
    h[4] = (_Float16)hi.x; h[5] = (_Float16)hi.y;
    h[6] = (_Float16)hi.z; h[7] = (_Float16)hi.w;
    *reinterpret_cast<half8*>(dst) = h;
}
__device__ __forceinline__ void cvt_write4(void* dst, float4 v) {
    half4v h;
    h[0] = (_Float16)v.x; h[1] = (_Float16)v.y;
    h[2] = (_Float16)v.z; h[3] = (_Float16)v.w;
    *reinterpret_cast<half4v*>(dst) = h;
}

__global__ __launch_bounds__(512, 2)
void rnn_mfma_kernel(const float* __restrict__ x, const float* __restrict__ h0,
                     const float* __restrict__ W, const float* __restrict__ bias,
                     float* __restrict__ out)
{
    __shared__ __align__(16) unsigned char lds[2 * BUF];

    const int tid  = threadIdx.x;
    const int lane = tid & 63;
    const int wv   = tid >> 6;     // wave 0..7, owns units [32wv, 32wv+32)
    const int l15  = lane & 15;
    const int quad = lane >> 4;
    const int b0   = blockIdx.x * 16;

    // ---- W fragments (B operand) + bias, one-time ----
    half8 wf[2][NSL];
    float bv[2];
#pragma unroll
    for (int nt = 0; nt < 2; ++nt) {
        const int n = 32 * wv + 16 * nt + l15;
        bv[nt] = bias[n];
#pragma unroll
        for (int s = 0; s < NSL; ++s) {
            half8 f;
#pragma unroll
            for (int j = 0; j < 8; ++j) {
                const int k = 32 * s + 8 * quad + j;
            f[j] = (_Float16)W[(size_t)k * U + n];
            }
            wf[nt][s] = f;
        }
    }

    // ---- stage h0 (slices 0..7) and x_0 (slices 8..11) into buffer 0 ----
    // 512 threads: h0 = 16 rows x 32 chunks of 8 units -> 1 chunk/thread.
    {
        const int sm = tid >> 5;          // batch row 0..15
        const int cc = tid & 31;          // unit chunk 0..31
        const float* hp = h0 + (size_t)(b0 + sm) * U + 8 * cc;
        cvt_write8(lds + (cc >> 2) * SS + (cc & 3) * QS + sm * 16,
                   *reinterpret_cast<const float4*>(hp),
                   *reinterpret_cast<const float4*>(hp + 4));
    }
    // x: 16 rows x 32 four-float chunks -> 1 per thread (8 B LDS write).
    const int sm = tid >> 5;              // batch row 0..15
    const int f4 = tid & 31;              // four-float chunk 0..31
    const int c8 = f4 >> 1;               // 8-unit chunk 0..15
    const float* xbase = x + (size_t)(b0 + sm) * T * D + 4 * f4;
    const int xslot = (8 + (c8 >> 2)) * SS + (c8 & 3) * QS + sm * 16 + (f4 & 1) * 8;
    cvt_write4(lds + xslot, *reinterpret_cast<const float4*>(xbase));

    // prefetch x row 1 (published to LDS during step 0)
    float4 p = *reinterpret_cast<const float4*>(xbase + D);

    __syncthreads();

    const int aoff = quad * QS + l15 * 16;

    for (int t = 0; t < T; ++t) {
        const int cur = t & 1, nxt = cur ^ 1;

        // issue prefetch for t+2 (consumed next step -> ~1 step of slack)
        const int tp = (t + 2 < T) ? (t + 2) : (T - 1);
        float4 q = *reinterpret_cast<const float4*>(xbase + (size_t)D * tp);

        // A fragments: [h_t | x_t]  (same for every wave)
        half8 a[NSL];
        const unsigned char* ab = lds + cur * BUF + aoff;
#pragma unroll
        for (int s = 0; s < NSL; ++s)
            a[s] = *reinterpret_cast<const half8*>(ab + s * SS);

        floatx4 acc[2];
#pragma unroll
        for (int nt = 0; nt < 2; ++nt)
            acc[nt] = (floatx4){bv[nt], bv[nt], bv[nt], bv[nt]};
#pragma unroll
        for (int s = 0; s < NSL; ++s)
#pragma unroll
            for (int nt = 0; nt < 2; ++nt)
                acc[nt] = __builtin_amdgcn_mfma_f32_16x16x32_f16(
                              a[s], wf[nt][s], acc[nt], 0, 0, 0);

        // epilogue: tanh, fp32 store, f16 publish into LDS[nxt] A-layout
        unsigned char* hb = lds + nxt * BUF;
        float* orow = out + (size_t)t * U;
#pragma unroll
        for (int nt = 0; nt < 2; ++nt) {
            const int n = 32 * wv + 16 * nt + l15;
#pragma unroll
            for (int r = 0; r < 4; ++r) {
                const int m = 4 * quad + r;
                const float h = fast_tanh(acc[nt][r]);
                orow[(size_t)(b0 + m) * T * U + n] = h;
                *reinterpret_cast<_Float16*>(
                    hb + (n >> 5) * SS + ((n >> 3) & 3) * QS + m * 16 + (n & 7) * 2)
                    = (_Float16)h;
            }
        }

        // publish x_{t+1} (loaded last step) into LDS[nxt] slices 8..11
        cvt_write4(hb + xslot, p);
        p = q;

        __syncthreads();
    }
}

extern "C" void kernel_launch(void* const* d_in, const int* in_sizes, int n_in,
                              void* d_out, int out_size, void* d_ws, size_t ws_size,
                              hipStream_t stream) {
    const float* x    = (const float*)d_in[0];
    const float* h0   = (const float*)d_in[1];
    const float* W    = (const float*)d_in[2];
    const float* bias = (const float*)d_in[3];
    float* out = (float*)d_out;

    hipLaunchKernelGGL(rnn_mfma_kernel, dim3(B / 16), dim3(512), 0, stream,
                       x, h0, W, bias, out);
}

// Round 3
// 1082.549 us; speedup vs baseline: 1.6456x; 1.1679x over previous
//
#include <hip/hip_runtime.h>

// MyRNNCell via MFMA f16 on gfx950 — v4: v3 + overlap/VALU trims.
//
//   Wh = W[0:256], Wx = W[256:384];  h_{t+1} = tanh([h_t | x_t] @ W + bias)
//
// Structure (unchanged from v3, 1000us): 16 WGs x 16 batches; 512 threads =
// 8 waves (2/SIMD); wave w owns units [32w,32w+32) = 2 N-tiles. K = 384 =
// 12 slices of 32 (h: 0..7, x_t: 8..11). Double-buffered LDS A-panel, one
// __syncthreads per step. x prefetched 2 steps ahead.
//
// v3 budget per step (2340 cyc on the 16 active CUs): MFMA pipe 932 cyc
// (192 MFMA/CU @ 19.4 cyc/SIMD), LDS pipe ~1150 cyc (8 waves x 12KB
// A-reads @ 85B/cy), VALU ~900 cyc -> floor ~= max ~= 1150-1300 cyc. v4
// attacks overlap + VALU at fixed structure:
//  1. t-loop unrolled x2: buffer bases are immediates, x-prefetch regs
//     rotate (no copies), no cur/nxt math.
//  2. W,bias pre-scaled by 2*log2(e): tanh = 1 - 2*rcp(exp2(acc)+1), one
//     v_mul per output dropped.
//  3. x-slices (frags + their 4 independent MFMAs) first: first MFMA
//     issues after 4 ds_reads, not 12.
//  4. Hoisted publish offsets + out pointers; epilogue order tanh(8) ->
//     global stores(8) -> LDS publishes(8): store acks age while lgkm
//     work runs before the barrier's full drain.
//  5. s_setprio(1) around the MFMA cluster (2 waves/SIMD slide phases
//     between barriers -> scheduler has something to arbitrate).
//
// fp16 (not bf16): 2^-11 quantization keeps recurrent error ~1e-3 << 2e-2.

typedef _Float16 half8 __attribute__((ext_vector_type(8)));
typedef _Float16 half4v __attribute__((ext_vector_type(4)));
typedef float floatx4 __attribute__((ext_vector_type(4)));

constexpr int B = 256, T = 1024, D = 128, U = 256;
constexpr int NSL = (U + D) / 32;      // 12 K-slices
constexpr int QS  = 16 * 16 + 16;      // 272 B quad stride (+16 pad: bank spread)
constexpr int SS  = 4 * QS;            // 1088 B slice stride
constexpr int BUF = NSL * SS;          // 13056 B per A-buffer

// 2*log2(e): acc is pre-scaled so tanh needs no multiply.
constexpr float TANH_K = 2.8853900817779268f;

__device__ __forceinline__ float fexp2(float v) {
#if __has_builtin(__builtin_amdgcn_exp2f)
    return __builtin_amdgcn_exp2f(v);
#else
    return exp2f(v);
#endif
}
__device__ __forceinline__ float frcp(float v) {
#if __has_builtin(__builtin_amdgcn_rcpf)
    return __builtin_amdgcn_rcpf(v);
#else
    return 1.0f / v;
#endif
}
// a = 2*log2(e)*v  ->  tanh(v) = 1 - 2/(2^a + 1).  exp2->inf, rcp(inf)=0
// make saturation exact at both ends without clamping.
__device__ __forceinline__ float tanh_prescaled(float a) {
    float e = fexp2(a);
    return 1.0f - 2.0f * frcp(e + 1.0f);
}

__device__ __forceinline__ void cvt_write8(void* dst, float4 lo, float4 hi) {
    half8 h;
    h[0] = (_Float16)lo.x; h[1] = (_Float16)lo.y;
    h[2] = (_Float16)lo.z; h[3] = (_Float16)lo.w;
    h[4] = (_Float16)hi.x; h[5] = (_Float16)hi.y;
    h[6] = (_Float16)hi.z; h[7] = (_Float16)hi.w;
    *reinterpret_cast<half8*>(dst) = h;
}
__device__ __forceinline__ void cvt_write4(void* dst, float4 v) {
    half4v h;
    h[0] = (_Float16)v.x; h[1] = (_Float16)v.y;
    h[2] = (_Float16)v.z; h[3] = (_Float16)v.w;
    *reinterpret_cast<half4v*>(dst) = h;
}

__global__ __launch_bounds__(512, 2)
void rnn_mfma_kernel(const float* __restrict__ x, const float* __restrict__ h0,
                     const float* __restrict__ W, const float* __restrict__ bias,
                     float* __restrict__ out)
{
    __shared__ __align__(16) unsigned char lds[2 * BUF];

    const int tid  = threadIdx.x;
    const int lane = tid & 63;
    const int wv   = tid >> 6;     // wave 0..7, owns units [32wv, 32wv+32)
    const int l15  = lane & 15;
    const int quad = lane >> 4;
    const int b0   = blockIdx.x * 16;

    // ---- W fragments (B operand) + bias, pre-scaled by TANH_K ----
    half8 wf[2][NSL];
    float bv[2];
#pragma unroll
    for (int nt = 0; nt < 2; ++nt) {
        const int n = 32 * wv + 16 * nt + l15;
        bv[nt] = bias[n] * TANH_K;
#pragma unroll
        for (int s = 0; s < NSL; ++s) {
            half8 f;
#pragma unroll
            for (int j = 0; j < 8; ++j) {
                const int k = 32 * s + 8 * quad + j;
                f[j] = (_Float16)(W[(size_t)k * U + n] * TANH_K);
            }
            wf[nt][s] = f;
        }
    }

    // ---- stage h0 (slices 0..7) and x_0 (slices 8..11) into buffer 0 ----
    {
        const int hm = tid >> 5;          // batch row 0..15
        const int cc = tid & 31;          // unit chunk 0..31
        const float* hp = h0 + (size_t)(b0 + hm) * U + 8 * cc;
        cvt_write8(lds + (cc >> 2) * SS + (cc & 3) * QS + hm * 16,
                   *reinterpret_cast<const float4*>(hp),
                   *reinterpret_cast<const float4*>(hp + 4));
    }
    const int sm = tid >> 5;              // batch row 0..15
    const int f4 = tid & 31;              // four-float chunk 0..31
    const int c8 = f4 >> 1;               // 8-unit chunk 0..15
    const float* xbase = x + (size_t)(b0 + sm) * T * D + 4 * f4;
    const int xslot = (8 + (c8 >> 2)) * SS + (c8 & 3) * QS + sm * 16 + (f4 & 1) * 8;
    cvt_write4(lds + xslot, *reinterpret_cast<const float4*>(xbase));

    // prefetch x row 1 (published to LDS during step 0)
    float4 p = *reinterpret_cast<const float4*>(xbase + D);
    float4 q;

    __syncthreads();

    const int aoff = quad * QS + l15 * 16;

    // hoisted epilogue constants: i = 4*nt + r -> n = 32wv+16nt+l15, m = 4quad+r
    floatx4 acc0[2];
#pragma unroll
    for (int nt = 0; nt < 2; ++nt)
        acc0[nt] = (floatx4){bv[nt], bv[nt], bv[nt], bv[nt]};
    float* optr[8];
    int    pubo[8];
#pragma unroll
    for (int i = 0; i < 8; ++i) {
        const int nt = i >> 2, r = i & 3;
        const int n = 32 * wv + 16 * nt + l15;
        const int m = 4 * quad + r;
        optr[i] = out + (size_t)(b0 + m) * T * U + n;
        pubo[i] = (n >> 5) * SS + ((n >> 3) & 3) * QS + m * 16 + (n & 7) * 2;
    }

    // One step. CO/NO are literal byte offsets of buffers t%2 / (t+1)%2.
    // PP holds x_{t+1} (published this step); QQ receives x_{t+2}.
#define STEP(tt, CO, NO, PP, QQ)                                               \
    do {                                                                       \
        const int t_ = (tt);                                                   \
        const int tp_ = (t_ + 2 < T) ? (t_ + 2) : (T - 1);                     \
        QQ = *reinterpret_cast<const float4*>(xbase + (size_t)D * tp_);        \
        const unsigned char* ab = lds + (CO) + aoff;                           \
        half8 ax[4];                                                           \
        _Pragma("unroll")                                                      \
        for (int s = 0; s < 4; ++s)                                            \
            ax[s] = *reinterpret_cast<const half8*>(ab + (8 + s) * SS);        \
        half8 ah[8];                                                           \
        _Pragma("unroll")                                                      \
        for (int s = 0; s < 8; ++s)                                            \
            ah[s] = *reinterpret_cast<const half8*>(ab + s * SS);              \
        floatx4 acc[2];                                                        \
        acc[0] = acc0[0]; acc[1] = acc0[1];                                    \
        __builtin_amdgcn_s_setprio(1);                                         \
        _Pragma("unroll")                                                      \
        for (int s = 0; s < 4; ++s)                                            \
            _Pragma("unroll")                                                  \
            for (int nt = 0; nt < 2; ++nt)                                     \
                acc[nt] = __builtin_amdgcn_mfma_f32_16x16x32_f16(              \
                              ax[s], wf[nt][8 + s], acc[nt], 0, 0, 0);         \
        _Pragma("unroll")                                                      \
        for (int s = 0; s < 8; ++s)                                            \
            _Pragma("unroll")                                                  \
            for (int nt = 0; nt < 2; ++nt)                                     \
                acc[nt] = __builtin_amdgcn_mfma_f32_16x16x32_f16(              \
                              ah[s], wf[nt][s], acc[nt], 0, 0, 0);             \
        __builtin_amdgcn_s_setprio(0);                                         \
        float hv[8];                                                           \
        _Pragma("unroll")                                                      \
        for (int i = 0; i < 8; ++i)                                            \
            hv[i] = tanh_prescaled(acc[i >> 2][i & 3]);                        \
        /* long-latency global stores first ... */                             \
        _Pragma("unroll")                                                      \
        for (int i = 0; i < 8; ++i)                                            \
            optr[i][(size_t)t_ * U] = hv[i];                                   \
        /* ... then LDS publishes (h_{t+1} + x_{t+1}) into buffer NO */        \
        _Pragma("unroll")                                                      \
        for (int i = 0; i < 8; ++i)                                            \
            *reinterpret_cast<_Float16*>(lds + (NO) + pubo[i]) =               \
                (_Float16)hv[i];                                               \
        cvt_write4(lds + (NO) + xslot, PP);                                    \
        __syncthreads();                                                       \
    } while (0)

    for (int t = 0; t < T; t += 2) {
        STEP(t,     0,   BUF, p, q);
        STEP(t + 1, BUF, 0,   q, p);
    }
#undef STEP
}

extern "C" void kernel_launch(void* const* d_in, const int* in_sizes, int n_in,
                              void* d_out, int out_size, void* d_ws, size_t ws_size,
                              hipStream_t stream) {
    const float* x    = (const float*)d_in[0];
    const float* h0   = (const float*)d_in[1];
    const float* W    = (const float*)d_in[2];
    const float* bias = (const float*)d_in[3];
    float* out = (float*)d_out;

    hipLaunchKernelGGL(rnn_mfma_kernel, dim3(B / 16), dim3(512), 0, stream,
                       x, h0, W, bias, out);
}